// Round 1
// baseline (124719.141 us; speedup 1.0000x reference)
//
#include <hip/hip_runtime.h>

#define N_NODES 50000
#define N_EDGES 800000
#define HID 64

// ---------------- workspace layout (floats) ----------------
// dinv  : N_NODES (padded to 50048)   -- also used as deg accumulator
// normv : N_EDGES
// xb0   : N_NODES*64
// xb1   : N_NODES*64
// xl    : N_NODES*64
// agg   : N_NODES*64
// total = 13,650,048 floats = 54.6 MB

__global__ __launch_bounds__(256) void k_deg(const int* __restrict__ dst, float* __restrict__ deg) {
    int e = blockIdx.x * 256 + threadIdx.x;
    if (e < N_EDGES) atomicAdd(&deg[dst[e]], 1.0f);
}

__global__ __launch_bounds__(256) void k_dinv(float* __restrict__ deg) {
    int i = blockIdx.x * 256 + threadIdx.x;
    if (i < N_NODES) deg[i] = rsqrtf(deg[i] + 1.0f);
}

__global__ __launch_bounds__(256) void k_norm(const int* __restrict__ src, const int* __restrict__ dst,
                                              const float* __restrict__ dinv, float* __restrict__ normv) {
    int e = blockIdx.x * 256 + threadIdx.x;
    if (e < N_EDGES) normv[e] = dinv[src[e]] * dinv[dst[e]];
}

// xl = x @ W   (one node row per thread, W staged in LDS, broadcast reads)
__global__ __launch_bounds__(256, 1) void k_xl(const float* __restrict__ x, const float* __restrict__ W,
                                               float* __restrict__ xl) {
    __shared__ float w[64 * 64];
    for (int i = threadIdx.x; i < 1024; i += 256)
        ((float4*)w)[i] = ((const float4*)W)[i];
    __syncthreads();
    int row = blockIdx.x * 256 + threadIdx.x;
    if (row >= N_NODES) return;

    float v[64];
    const float4* xr = (const float4*)(x + (size_t)row * 64);
#pragma unroll
    for (int i = 0; i < 16; ++i) {
        float4 t = xr[i];
        v[4 * i] = t.x; v[4 * i + 1] = t.y; v[4 * i + 2] = t.z; v[4 * i + 3] = t.w;
    }
    float acc[64];
#pragma unroll
    for (int j = 0; j < 64; ++j) acc[j] = 0.f;
#pragma unroll
    for (int k = 0; k < 64; ++k) {
        float xv = v[k];
#pragma unroll
        for (int j4 = 0; j4 < 16; ++j4) {
            float4 wv = ((const float4*)w)[k * 16 + j4];
            acc[4 * j4 + 0] = fmaf(xv, wv.x, acc[4 * j4 + 0]);
            acc[4 * j4 + 1] = fmaf(xv, wv.y, acc[4 * j4 + 1]);
            acc[4 * j4 + 2] = fmaf(xv, wv.z, acc[4 * j4 + 2]);
            acc[4 * j4 + 3] = fmaf(xv, wv.w, acc[4 * j4 + 3]);
        }
    }
    float4* xo = (float4*)(xl + (size_t)row * 64);
#pragma unroll
    for (int i = 0; i < 16; ++i)
        xo[i] = make_float4(acc[4 * i], acc[4 * i + 1], acc[4 * i + 2], acc[4 * i + 3]);
}

// agg[dst] += norm * xl[src]   -- one wave per edge (64 lanes = 64 cols)
__global__ __launch_bounds__(256) void k_scatter(const int* __restrict__ src, const int* __restrict__ dst,
                                                 const float* __restrict__ normv, const float* __restrict__ xl,
                                                 float* __restrict__ agg) {
    int idx = blockIdx.x * 256 + threadIdx.x;   // over E*64 = 51.2M exactly
    int e = idx >> 6;
    int j = idx & 63;
    float v = normv[e] * xl[(size_t)src[e] * 64 + j];
    atomicAdd(&agg[(size_t)dst[e] * 64 + j], v);
}

// x_out = relu(agg + dinv^2 * xl + b)
__global__ __launch_bounds__(256) void k_fin(const float* __restrict__ agg, const float* __restrict__ xl,
                                             const float* __restrict__ dinv, const float* __restrict__ b,
                                             float* __restrict__ xout) {
    int idx = blockIdx.x * 256 + threadIdx.x;   // over N*64 = 3.2M exactly
    int n = idx >> 6;
    int j = idx & 63;
    float sn = dinv[n];
    sn *= sn;
    float val = agg[idx] + sn * xl[idx] + b[j];
    xout[idx] = fmaxf(val, 0.f);
}

// Fused edge pipeline: edge MLP (8 layers) + concat-out MLP (192-K as 3 chunks)
// + 3 out layers + final dot. One edge per thread; weights streamed via 16KB LDS.
__global__ __launch_bounds__(256, 1) void k_edge_mega(
    const float* __restrict__ edge_attr, const int* __restrict__ src, const int* __restrict__ dst,
    const float* __restrict__ xfin,
    const float* __restrict__ ew0, const float* __restrict__ eb0,
    const float* __restrict__ ew,  const float* __restrict__ eb,
    const float* __restrict__ ow0, const float* __restrict__ ob0,
    const float* __restrict__ ow,  const float* __restrict__ ob,
    const float* __restrict__ finw, const float* __restrict__ finb,
    float* __restrict__ out) {
    __shared__ float wlds[4096];
    __shared__ float blds[64];
    const int tid = threadIdx.x;
    const int e = blockIdx.x * 256 + tid;   // E = 3125*256 exactly
    const int se = src[e];
    const int de = dst[e];

    float v[64], acc[64];

    // ---- layer 0: e = relu(edge_attr @ ew0 + eb0), K = 16 ----
    if (tid < 256) ((float4*)wlds)[tid] = ((const float4*)ew0)[tid];   // 1024 floats
    if (tid < 16)  ((float4*)blds)[tid] = ((const float4*)eb0)[tid];
    __syncthreads();
    {
        float a[16];
        const float4* ar = (const float4*)(edge_attr + (size_t)e * 16);
#pragma unroll
        for (int i = 0; i < 4; ++i) {
            float4 t = ar[i];
            a[4 * i] = t.x; a[4 * i + 1] = t.y; a[4 * i + 2] = t.z; a[4 * i + 3] = t.w;
        }
#pragma unroll
        for (int j = 0; j < 64; ++j) acc[j] = blds[j];
#pragma unroll
        for (int k = 0; k < 16; ++k) {
            float xv = a[k];
#pragma unroll
            for (int j4 = 0; j4 < 16; ++j4) {
                float4 wv = ((const float4*)wlds)[k * 16 + j4];
                acc[4 * j4 + 0] = fmaf(xv, wv.x, acc[4 * j4 + 0]);
                acc[4 * j4 + 1] = fmaf(xv, wv.y, acc[4 * j4 + 1]);
                acc[4 * j4 + 2] = fmaf(xv, wv.z, acc[4 * j4 + 2]);
                acc[4 * j4 + 3] = fmaf(xv, wv.w, acc[4 * j4 + 3]);
            }
        }
#pragma unroll
        for (int j = 0; j < 64; ++j) v[j] = fmaxf(acc[j], 0.f);
    }

    // ---- 13 staged K=64 FMA stages (7 edge layers, 3 ow0 chunks, 3 out layers) ----
    for (int s = 0; s < 13; ++s) {
        const float* wp;
        const float* bp;
        int vupd;   // 0: v = relu(acc);  1: v = x[src];  2: v = x[dst]
        if (s < 7)       { wp = ew + s * 4096;        bp = eb + s * 64;        vupd = 0; }
        else if (s == 7) { wp = ow0 + 128 * 64;       bp = ob0;                vupd = 1; }   // e-part of concat
        else if (s == 8) { wp = ow0;                  bp = nullptr;            vupd = 2; }   // x[src] part
        else if (s == 9) { wp = ow0 + 64 * 64;        bp = nullptr;            vupd = 0; }   // x[dst] part
        else             { wp = ow + (s - 10) * 4096; bp = ob + (s - 10) * 64; vupd = 0; }

        __syncthreads();
        for (int i = tid; i < 1024; i += 256)
            ((float4*)wlds)[i] = ((const float4*)wp)[i];
        if (bp != nullptr && tid < 16)
            ((float4*)blds)[tid] = ((const float4*)bp)[tid];
        __syncthreads();

        if (bp != nullptr) {
#pragma unroll
            for (int j = 0; j < 64; ++j) acc[j] = blds[j];
        }
#pragma unroll
        for (int k = 0; k < 64; ++k) {
            float xv = v[k];
#pragma unroll
            for (int j4 = 0; j4 < 16; ++j4) {
                float4 wv = ((const float4*)wlds)[k * 16 + j4];
                acc[4 * j4 + 0] = fmaf(xv, wv.x, acc[4 * j4 + 0]);
                acc[4 * j4 + 1] = fmaf(xv, wv.y, acc[4 * j4 + 1]);
                acc[4 * j4 + 2] = fmaf(xv, wv.z, acc[4 * j4 + 2]);
                acc[4 * j4 + 3] = fmaf(xv, wv.w, acc[4 * j4 + 3]);
            }
        }
        if (vupd == 0) {
#pragma unroll
            for (int j = 0; j < 64; ++j) v[j] = fmaxf(acc[j], 0.f);
        } else {
            const float4* xr = (const float4*)(xfin + (size_t)(vupd == 1 ? se : de) * 64);
#pragma unroll
            for (int i = 0; i < 16; ++i) {
                float4 t = xr[i];
                v[4 * i] = t.x; v[4 * i + 1] = t.y; v[4 * i + 2] = t.z; v[4 * i + 3] = t.w;
            }
        }
    }

    // ---- final: out = v . fin_w + fin_b ----
    float o = finb[0];
#pragma unroll
    for (int k = 0; k < 64; ++k) o = fmaf(v[k], finw[k], o);
    out[e] = o;
}

extern "C" void kernel_launch(void* const* d_in, const int* in_sizes, int n_in,
                              void* d_out, int out_size, void* d_ws, size_t ws_size,
                              hipStream_t stream) {
    (void)in_sizes; (void)n_in; (void)out_size; (void)ws_size;

    const float* x         = (const float*)d_in[0];
    const int*   src       = (const int*)d_in[1];
    const int*   dst       = (const int*)d_in[2];
    const float* edge_attr = (const float*)d_in[3];
    const float* gcn_w     = (const float*)d_in[4];
    const float* gcn_b     = (const float*)d_in[5];
    const float* edge_w0   = (const float*)d_in[6];
    const float* edge_b0   = (const float*)d_in[7];
    const float* edge_w    = (const float*)d_in[8];
    const float* edge_b    = (const float*)d_in[9];
    const float* out_w0    = (const float*)d_in[10];
    const float* out_b0    = (const float*)d_in[11];
    const float* out_w     = (const float*)d_in[12];
    const float* out_b     = (const float*)d_in[13];
    const float* fin_w     = (const float*)d_in[14];
    const float* fin_b     = (const float*)d_in[15];
    float* out = (float*)d_out;

    float* ws    = (float*)d_ws;
    float* dinv  = ws;                       // N (as deg first)
    float* normv = ws + 50048;               // E
    float* xb0   = normv + N_EDGES;          // N*64
    float* xb1   = xb0 + N_NODES * 64;
    float* xl    = xb1 + N_NODES * 64;
    float* agg   = xl + N_NODES * 64;

    const int EB = N_EDGES / 256;            // 3125
    const int NB = (N_NODES + 255) / 256;    // 196

    hipMemsetAsync(dinv, 0, N_NODES * sizeof(float), stream);
    k_deg<<<EB, 256, 0, stream>>>(dst, dinv);
    k_dinv<<<NB, 256, 0, stream>>>(dinv);
    k_norm<<<EB, 256, 0, stream>>>(src, dst, dinv, normv);

    const float* xin = x;
    float* bufs[2] = {xb0, xb1};
    for (int layer = 0; layer < 4; ++layer) {
        float* xout = bufs[layer & 1];
        k_xl<<<NB, 256, 0, stream>>>(xin, gcn_w + layer * 4096, xl);
        hipMemsetAsync(agg, 0, (size_t)N_NODES * 64 * sizeof(float), stream);
        k_scatter<<<N_EDGES * 64 / 256, 256, 0, stream>>>(src, dst, normv, xl, agg);
        k_fin<<<N_NODES * 64 / 256, 256, 0, stream>>>(agg, xl, dinv, gcn_b + layer * 64, xout);
        xin = xout;
    }
    // final x is in xb1 (layers 0,1,2,3 -> xb0,xb1,xb0,xb1)

    k_edge_mega<<<EB, 256, 0, stream>>>(edge_attr, src, dst, xb1,
                                        edge_w0, edge_b0, edge_w, edge_b,
                                        out_w0, out_b0, out_w, out_b,
                                        fin_w, fin_b, out);
}

// Round 2
// 118028.308 us; speedup vs baseline: 1.0567x; 1.0567x over previous
//
#include <hip/hip_runtime.h>

#define N_NODES 50000
#define N_EDGES 800000

// fused-multiply-add one weight row (64 outputs) into acc[64]; Wp = float4* LDS
#define FMA_ROW(Wp, xv, krow)                                        \
  {                                                                  \
    _Pragma("unroll") for (int j4 = 0; j4 < 16; ++j4) {              \
      float4 wv = (Wp)[(krow) * 16 + j4];                            \
      acc[4 * j4 + 0] = fmaf((xv), wv.x, acc[4 * j4 + 0]);           \
      acc[4 * j4 + 1] = fmaf((xv), wv.y, acc[4 * j4 + 1]);           \
      acc[4 * j4 + 2] = fmaf((xv), wv.z, acc[4 * j4 + 2]);           \
      acc[4 * j4 + 3] = fmaf((xv), wv.w, acc[4 * j4 + 3]);           \
    }                                                                \
  }

__global__ __launch_bounds__(256) void k_deg(const int* __restrict__ dst, float* __restrict__ deg) {
    int e = blockIdx.x * 256 + threadIdx.x;
    if (e < N_EDGES) atomicAdd(&deg[dst[e]], 1.0f);
}

__global__ __launch_bounds__(256) void k_dinv(float* __restrict__ deg) {
    int i = blockIdx.x * 256 + threadIdx.x;
    if (i < N_NODES) deg[i] = rsqrtf(deg[i] + 1.0f);
}

__global__ __launch_bounds__(256) void k_norm(const int* __restrict__ src, const int* __restrict__ dst,
                                              const float* __restrict__ dinv, float* __restrict__ normv) {
    int e = blockIdx.x * 256 + threadIdx.x;
    if (e < N_EDGES) normv[e] = dinv[src[e]] * dinv[dst[e]];
}

// xl = x @ W : one row per thread, activations staged via LDS column to keep VGPRs low
__global__ __launch_bounds__(128, 1) void k_xl(const float* __restrict__ x, const float* __restrict__ W,
                                               float* __restrict__ xl) {
    __shared__ float4 act[16 * 128];   // [k4][tid] 32KB
    __shared__ float4 wl[1024];        // 16KB
    const int tid = threadIdx.x;
    for (int i = tid; i < 1024; i += 128) wl[i] = ((const float4*)W)[i];
    __syncthreads();
    const int row = blockIdx.x * 128 + tid;
    if (row >= N_NODES) return;        // no further __syncthreads below

    const float4* xr = (const float4*)(x + (size_t)row * 64);
#pragma unroll
    for (int i = 0; i < 16; ++i) act[i * 128 + tid] = xr[i];

    float acc[64];
#pragma unroll
    for (int j = 0; j < 64; ++j) acc[j] = 0.f;
#pragma unroll
    for (int k4 = 0; k4 < 16; ++k4) {
        float4 v4 = act[k4 * 128 + tid];
        FMA_ROW(wl, v4.x, 4 * k4 + 0)
        FMA_ROW(wl, v4.y, 4 * k4 + 1)
        FMA_ROW(wl, v4.z, 4 * k4 + 2)
        FMA_ROW(wl, v4.w, 4 * k4 + 3)
    }
    float4* xo = (float4*)(xl + (size_t)row * 64);
#pragma unroll
    for (int i = 0; i < 16; ++i)
        xo[i] = make_float4(acc[4 * i], acc[4 * i + 1], acc[4 * i + 2], acc[4 * i + 3]);
}

// agg[dst] += norm * xl[src]  -- wave-uniform edge index, 64 lanes = 64 cols
__global__ __launch_bounds__(256) void k_scatter(const int* __restrict__ src, const int* __restrict__ dst,
                                                 const float* __restrict__ normv, const float* __restrict__ xl,
                                                 float* __restrict__ agg) {
    int idx = blockIdx.x * 256 + threadIdx.x;
    int e = idx >> 6;
    int j = idx & 63;
    float v = normv[e] * xl[(size_t)src[e] * 64 + j];
    atomicAdd(&agg[(size_t)dst[e] * 64 + j], v);
}

__global__ __launch_bounds__(256) void k_fin(const float* __restrict__ agg, const float* __restrict__ xl,
                                             const float* __restrict__ dinv, const float* __restrict__ b,
                                             float* __restrict__ xout) {
    int idx = blockIdx.x * 256 + threadIdx.x;
    int n = idx >> 6;
    int j = idx & 63;
    float sn = dinv[n];
    sn *= sn;
    float val = agg[idx] + sn * xl[idx] + b[j];
    xout[idx] = fmaxf(val, 0.f);
}

// Fused edge pipeline, LDS-resident activations (one column per thread).
__global__ __launch_bounds__(128, 1) void k_edge_mega(
    const float* __restrict__ edge_attr, const int* __restrict__ src, const int* __restrict__ dst,
    const float* __restrict__ xfin,
    const float* __restrict__ ew0, const float* __restrict__ eb0,
    const float* __restrict__ ew,  const float* __restrict__ eb,
    const float* __restrict__ ow0, const float* __restrict__ ob0,
    const float* __restrict__ ow,  const float* __restrict__ ob,
    const float* __restrict__ finw, const float* __restrict__ finb,
    float* __restrict__ out) {
    __shared__ float4 act[16 * 128];   // activation tile, [k4][tid], 32KB
    __shared__ float4 wlds[1024];      // weight tile, 16KB
    __shared__ float  blds[64];
    const int tid = threadIdx.x;
    const int e = blockIdx.x * 128 + tid;   // E = 6250*128 exactly
    const int se = src[e];
    const int de = dst[e];

    float acc[64];

    // ---- layer 0: e = relu(edge_attr @ ew0 + eb0), K = 16 ----
    for (int i = tid; i < 256; i += 128) wlds[i] = ((const float4*)ew0)[i];
    if (tid < 16) ((float4*)blds)[tid] = ((const float4*)eb0)[tid];
    __syncthreads();
    {
        const float4* ar = (const float4*)(edge_attr + (size_t)e * 16);
        float4 a0 = ar[0], a1 = ar[1], a2 = ar[2], a3 = ar[3];
#pragma unroll
        for (int j = 0; j < 64; ++j) acc[j] = blds[j];
        FMA_ROW(wlds, a0.x, 0)  FMA_ROW(wlds, a0.y, 1)  FMA_ROW(wlds, a0.z, 2)  FMA_ROW(wlds, a0.w, 3)
        FMA_ROW(wlds, a1.x, 4)  FMA_ROW(wlds, a1.y, 5)  FMA_ROW(wlds, a1.z, 6)  FMA_ROW(wlds, a1.w, 7)
        FMA_ROW(wlds, a2.x, 8)  FMA_ROW(wlds, a2.y, 9)  FMA_ROW(wlds, a2.z, 10) FMA_ROW(wlds, a2.w, 11)
        FMA_ROW(wlds, a3.x, 12) FMA_ROW(wlds, a3.y, 13) FMA_ROW(wlds, a3.z, 14) FMA_ROW(wlds, a3.w, 15)
#pragma unroll
        for (int j4 = 0; j4 < 16; ++j4)
            act[j4 * 128 + tid] = make_float4(fmaxf(acc[4 * j4], 0.f), fmaxf(acc[4 * j4 + 1], 0.f),
                                              fmaxf(acc[4 * j4 + 2], 0.f), fmaxf(acc[4 * j4 + 3], 0.f));
    }

    // ---- 13 staged K=64 stages: 7 edge layers, 3 ow0 chunks, 3 out layers ----
    for (int s = 0; s < 13; ++s) {
        const float* wp;
        const float* bp;
        int vupd;   // 0: act = relu(acc);  1: act = x[src];  2: act = x[dst]
        if (s < 7)       { wp = ew + s * 4096;        bp = eb + s * 64;        vupd = 0; }
        else if (s == 7) { wp = ow0 + 128 * 64;       bp = ob0;                vupd = 1; }
        else if (s == 8) { wp = ow0;                  bp = nullptr;            vupd = 2; }
        else if (s == 9) { wp = ow0 + 64 * 64;        bp = nullptr;            vupd = 0; }
        else             { wp = ow + (s - 10) * 4096; bp = ob + (s - 10) * 64; vupd = 0; }

        __syncthreads();
        for (int i = tid; i < 1024; i += 128) wlds[i] = ((const float4*)wp)[i];
        if (bp != nullptr && tid < 16) ((float4*)blds)[tid] = ((const float4*)bp)[tid];
        __syncthreads();

        if (bp != nullptr) {
#pragma unroll
            for (int j = 0; j < 64; ++j) acc[j] = blds[j];
        }
#pragma unroll
        for (int k4 = 0; k4 < 16; ++k4) {
            float4 v4 = act[k4 * 128 + tid];
            FMA_ROW(wlds, v4.x, 4 * k4 + 0)
            FMA_ROW(wlds, v4.y, 4 * k4 + 1)
            FMA_ROW(wlds, v4.z, 4 * k4 + 2)
            FMA_ROW(wlds, v4.w, 4 * k4 + 3)
        }

        if (vupd == 0) {
#pragma unroll
            for (int j4 = 0; j4 < 16; ++j4)
                act[j4 * 128 + tid] = make_float4(fmaxf(acc[4 * j4], 0.f), fmaxf(acc[4 * j4 + 1], 0.f),
                                                  fmaxf(acc[4 * j4 + 2], 0.f), fmaxf(acc[4 * j4 + 3], 0.f));
        } else {
            const float4* xr = (const float4*)(xfin + (size_t)(vupd == 1 ? se : de) * 64);
#pragma unroll
            for (int i = 0; i < 16; ++i) act[i * 128 + tid] = xr[i];
        }
    }

    // ---- final: out = act . fin_w + fin_b ----
    __syncthreads();
    if (tid < 16) wlds[tid] = ((const float4*)finw)[tid];
    __syncthreads();
    float o = finb[0];
#pragma unroll
    for (int k4 = 0; k4 < 16; ++k4) {
        float4 v4 = act[k4 * 128 + tid];
        float4 w4 = wlds[k4];
        o = fmaf(v4.x, w4.x, o);
        o = fmaf(v4.y, w4.y, o);
        o = fmaf(v4.z, w4.z, o);
        o = fmaf(v4.w, w4.w, o);
    }
    out[e] = o;
}

extern "C" void kernel_launch(void* const* d_in, const int* in_sizes, int n_in,
                              void* d_out, int out_size, void* d_ws, size_t ws_size,
                              hipStream_t stream) {
    (void)in_sizes; (void)n_in; (void)out_size; (void)ws_size;

    const float* x         = (const float*)d_in[0];
    const int*   src       = (const int*)d_in[1];
    const int*   dst       = (const int*)d_in[2];
    const float* edge_attr = (const float*)d_in[3];
    const float* gcn_w     = (const float*)d_in[4];
    const float* gcn_b     = (const float*)d_in[5];
    const float* edge_w0   = (const float*)d_in[6];
    const float* edge_b0   = (const float*)d_in[7];
    const float* edge_w    = (const float*)d_in[8];
    const float* edge_b    = (const float*)d_in[9];
    const float* out_w0    = (const float*)d_in[10];
    const float* out_b0    = (const float*)d_in[11];
    const float* out_w     = (const float*)d_in[12];
    const float* out_b     = (const float*)d_in[13];
    const float* fin_w     = (const float*)d_in[14];
    const float* fin_b     = (const float*)d_in[15];
    float* out = (float*)d_out;

    float* ws    = (float*)d_ws;
    float* dinv  = ws;                       // N (deg first)
    float* normv = ws + 50048;               // E
    float* xb0   = normv + N_EDGES;          // N*64
    float* xb1   = xb0 + N_NODES * 64;
    float* xl    = xb1 + N_NODES * 64;
    float* agg   = xl + N_NODES * 64;

    const int EB = N_EDGES / 256;            // 3125
    const int NB = (N_NODES + 255) / 256;    // 196

    hipMemsetAsync(dinv, 0, N_NODES * sizeof(float), stream);
    k_deg<<<EB, 256, 0, stream>>>(dst, dinv);
    k_dinv<<<NB, 256, 0, stream>>>(dinv);
    k_norm<<<EB, 256, 0, stream>>>(src, dst, dinv, normv);

    const float* xin = x;
    float* bufs[2] = {xb0, xb1};
    for (int layer = 0; layer < 4; ++layer) {
        float* xout = bufs[layer & 1];
        k_xl<<<(N_NODES + 127) / 128, 128, 0, stream>>>(xin, gcn_w + layer * 4096, xl);
        hipMemsetAsync(agg, 0, (size_t)N_NODES * 64 * sizeof(float), stream);
        k_scatter<<<N_EDGES * 64 / 256, 256, 0, stream>>>(src, dst, normv, xl, agg);
        k_fin<<<N_NODES * 64 / 256, 256, 0, stream>>>(agg, xl, dinv, gcn_b + layer * 64, xout);
        xin = xout;
    }

    k_edge_mega<<<N_EDGES / 128, 128, 0, stream>>>(edge_attr, src, dst, xb1,
                                                   edge_w0, edge_b0, edge_w, edge_b,
                                                   out_w0, out_b0, out_w, out_b,
                                                   fin_w, fin_b, out);
}

// Round 3
// 1174.548 us; speedup vs baseline: 106.1848x; 100.4882x over previous
//
#include <hip/hip_runtime.h>

#define N_NODES 50000
#define N_EDGES 800000

typedef __attribute__((ext_vector_type(8))) short short8v;   // 8 bf16 (4 VGPR)
typedef __attribute__((ext_vector_type(4))) float f32x4;

union U4S8 { uint4 u; short8v s; };
__device__ __forceinline__ short8v as_frag(uint4 u) { U4S8 t; t.u = u; return t.s; }
__device__ __forceinline__ uint4 zero4() { return make_uint4(0u, 0u, 0u, 0u); }

// ---------------- GCN helper kernels ----------------

__global__ __launch_bounds__(256) void k_deg(const int* __restrict__ dst, float* __restrict__ deg) {
    int e = blockIdx.x * 256 + threadIdx.x;
    if (e < N_EDGES) atomicAdd(&deg[dst[e]], 1.0f);
}

__global__ __launch_bounds__(256) void k_dinv(float* __restrict__ deg) {
    int i = blockIdx.x * 256 + threadIdx.x;
    if (i < N_NODES) deg[i] = rsqrtf(deg[i] + 1.0f);
}

__global__ __launch_bounds__(256) void k_norm(const int* __restrict__ src, const int* __restrict__ dst,
                                              const float* __restrict__ dinv, float* __restrict__ normv) {
    int e = blockIdx.x * 256 + threadIdx.x;
    if (e < N_EDGES) normv[e] = dinv[src[e]] * dinv[dst[e]];
}

// xl = x @ W : 64 rows/block, 4 threads per row (16 outputs each; acc[16] -> no spill)
__global__ __launch_bounds__(256, 2) void k_xl2(const float* __restrict__ x,
                                                const float* __restrict__ W,
                                                float* __restrict__ xl) {
    __shared__ float xs[64 * 68];
    __shared__ float ws[64 * 64];
    const int tid = threadIdx.x;
    const int rb = blockIdx.x * 64;
    for (int i = tid; i < 1024; i += 256) ((float4*)ws)[i] = ((const float4*)W)[i];
    for (int i = tid; i < 1024; i += 256) {
        int r = i >> 4, c = i & 15;
        int row = rb + r;
        float4 v = (row < N_NODES) ? ((const float4*)(x + (size_t)row * 64))[c] : make_float4(0, 0, 0, 0);
        *(float4*)(xs + r * 68 + c * 4) = v;
    }
    __syncthreads();
    const int r = tid >> 2, q = tid & 3;
    const int row = rb + r;
    float acc[16];
#pragma unroll
    for (int j = 0; j < 16; ++j) acc[j] = 0.f;
    const float* xrow = xs + r * 68;
#pragma unroll 4
    for (int k = 0; k < 64; ++k) {
        float xv = xrow[k];
        const float4* wr = (const float4*)(ws + k * 64 + q * 16);
#pragma unroll
        for (int j4 = 0; j4 < 4; ++j4) {
            float4 w4 = wr[j4];
            acc[4 * j4 + 0] = fmaf(xv, w4.x, acc[4 * j4 + 0]);
            acc[4 * j4 + 1] = fmaf(xv, w4.y, acc[4 * j4 + 1]);
            acc[4 * j4 + 2] = fmaf(xv, w4.z, acc[4 * j4 + 2]);
            acc[4 * j4 + 3] = fmaf(xv, w4.w, acc[4 * j4 + 3]);
        }
    }
    if (row < N_NODES) {
        float4* o = (float4*)(xl + (size_t)row * 64 + q * 16);
#pragma unroll
        for (int j4 = 0; j4 < 4; ++j4)
            o[j4] = make_float4(acc[4 * j4], acc[4 * j4 + 1], acc[4 * j4 + 2], acc[4 * j4 + 3]);
    }
}

__global__ __launch_bounds__(256) void k_scatter(const int* __restrict__ src, const int* __restrict__ dst,
                                                 const float* __restrict__ normv, const float* __restrict__ xl,
                                                 float* __restrict__ agg) {
    int idx = blockIdx.x * 256 + threadIdx.x;
    int e = idx >> 6;
    int j = idx & 63;
    float v = normv[e] * xl[(size_t)src[e] * 64 + j];
    atomicAdd(&agg[(size_t)dst[e] * 64 + j], v);
}

__global__ __launch_bounds__(256) void k_fin(const float* __restrict__ agg, const float* __restrict__ xl,
                                             const float* __restrict__ dinv, const float* __restrict__ b,
                                             float* __restrict__ xout) {
    int idx = blockIdx.x * 256 + threadIdx.x;
    int n = idx >> 6;
    int j = idx & 63;
    float sn = dinv[n];
    sn *= sn;
    float val = agg[idx] + sn * xl[idx] + b[j];
    xout[idx] = fmaxf(val, 0.f);
}

// ---------------- weight / bias pre-split ----------------
// wpk layout (u32): [s(14)][kt(2)][nt(4)][lane(64)][8] ; first 4 u32 = hi bf16x8 frag, last 4 = lo.
// k index per lane: k = kt*32 + (lane>>4)*8 + i  (same sigma used by all A-side packers -> cancels)
// n index per lane: n = nt*16 + (lane&15)

__global__ __launch_bounds__(256) void k_wprep(const float* __restrict__ ew0, const float* __restrict__ ew,
                                               const float* __restrict__ ow0, const float* __restrict__ ow,
                                               unsigned* __restrict__ wpk) {
    int t = blockIdx.x * 256 + threadIdx.x;
    if (t >= 14 * 512) return;
    int lane = t & 63;
    int nt = (t >> 6) & 3;
    int kt = (t >> 8) & 1;
    int s = t >> 9;
    int n = nt * 16 + (lane & 15);
    unsigned hu[8], lu[8];
#pragma unroll
    for (int i = 0; i < 8; ++i) {
        int k = kt * 32 + ((lane >> 4) * 8) + i;
        float w = 0.f;
        if (s == 0)       { if (k < 16) w = ew0[k * 64 + n]; }
        else if (s <= 7)  w = ew[((s - 1) * 64 + k) * 64 + n];
        else if (s == 8)  w = ow0[(128 + k) * 64 + n];
        else if (s == 9)  w = ow0[k * 64 + n];
        else if (s == 10) w = ow0[(64 + k) * 64 + n];
        else              w = ow[((s - 11) * 64 + k) * 64 + n];
        unsigned u = __float_as_uint(w);
        unsigned h = u & 0xFFFF0000u;
        float d = w - __uint_as_float(h);
        hu[i] = h >> 16;
        lu[i] = __float_as_uint(d) >> 16;
    }
    uint4* o = (uint4*)(wpk + (size_t)t * 8);
    o[0] = make_uint4(hu[0] | (hu[1] << 16), hu[2] | (hu[3] << 16), hu[4] | (hu[5] << 16), hu[6] | (hu[7] << 16));
    o[1] = make_uint4(lu[0] | (lu[1] << 16), lu[2] | (lu[3] << 16), lu[4] | (lu[5] << 16), lu[6] | (lu[7] << 16));
}

__global__ __launch_bounds__(256) void k_bprep(const float* __restrict__ eb0, const float* __restrict__ eb,
                                               const float* __restrict__ ob0, const float* __restrict__ ob,
                                               float* __restrict__ biasArr) {
    int t = blockIdx.x * 256 + threadIdx.x;
    if (t >= 14 * 64) return;
    int s = t >> 6, j = t & 63;
    float b = 0.f;
    if (s == 0) b = eb0[j];
    else if (s <= 7) b = eb[(s - 1) * 64 + j];
    else if (s == 8) b = ob0[j];
    else if (s >= 11) b = ob[(s - 11) * 64 + j];
    biasArr[t] = b;
}

// ---------------- fused edge mega kernel (MFMA, split bf16) ----------------
// 256 thr / 4 waves / block; wave owns 2 M-tiles (32 edges); block = 128 edges.
// act LDS: per (wave,mt) u32 tile [16 rows][68] (stride-68 pad), wave-private -> no barriers.

#define ACT_STRIDE 68
#define ACT_TILE (16 * ACT_STRIDE)   // 1088 u32 per M-tile

__device__ __forceinline__ void split_pack8(const float* xv, uint4& hfrag, uint4& lfrag) {
    unsigned hu[8], lu[8];
#pragma unroll
    for (int i = 0; i < 8; ++i) {
        unsigned u = __float_as_uint(xv[i]);
        unsigned h = u & 0xFFFF0000u;
        float d = xv[i] - __uint_as_float(h);
        hu[i] = h >> 16;
        lu[i] = __float_as_uint(d) >> 16;
    }
    hfrag = make_uint4(hu[0] | (hu[1] << 16), hu[2] | (hu[3] << 16), hu[4] | (hu[5] << 16), hu[6] | (hu[7] << 16));
    lfrag = make_uint4(lu[0] | (lu[1] << 16), lu[2] | (lu[3] << 16), lu[4] | (lu[5] << 16), lu[6] | (lu[7] << 16));
}

__device__ __forceinline__ void load_a_global_kt(const float* rowp, int kt, int g, uint4& aH, uint4& aL) {
    const float4* r4 = (const float4*)(rowp + kt * 32 + g * 8);
    float4 f0 = r4[0], f1 = r4[1];
    float xv[8] = {f0.x, f0.y, f0.z, f0.w, f1.x, f1.y, f1.z, f1.w};
    split_pack8(xv, aH, aL);
}

__device__ __forceinline__ void read_a_lds(const unsigned* actw, int mt, int l15, int g,
                                           uint4 aH[2][2], uint4 aL[2][2]) {
#pragma unroll
    for (int kt = 0; kt < 2; ++kt) {
        const unsigned* p = actw + mt * ACT_TILE + l15 * ACT_STRIDE + kt * 32 + g * 8;
        uint4 p0 = *(const uint4*)p;
        uint4 p1 = *(const uint4*)(p + 4);
        unsigned q[8] = {p0.x, p0.y, p0.z, p0.w, p1.x, p1.y, p1.z, p1.w};
        unsigned h[4], l[4];
#pragma unroll
        for (int j = 0; j < 4; ++j) {
            h[j] = (q[2 * j] >> 16) | (q[2 * j + 1] & 0xFFFF0000u);
            l[j] = (q[2 * j] & 0xFFFFu) | (q[2 * j + 1] << 16);
        }
        aH[mt][kt] = make_uint4(h[0], h[1], h[2], h[3]);
        aL[mt][kt] = make_uint4(l[0], l[1], l[2], l[3]);
    }
}

__device__ __forceinline__ void write_act(unsigned* actw, int mt, int l15, int g, f32x4 acc[2][4]) {
#pragma unroll
    for (int nt = 0; nt < 4; ++nt) {
        f32x4 a = acc[mt][nt];
#pragma unroll
        for (int r = 0; r < 4; ++r) {
            float x = fmaxf(a[r], 0.f);                         // relu before split
            unsigned u = __float_as_uint(x);
            unsigned h = u & 0xFFFF0000u;
            float d = x - __uint_as_float(h);
            unsigned pk = h | (__float_as_uint(d) >> 16);       // hi in top16, lo in low16
            actw[mt * ACT_TILE + (g * 4 + r) * ACT_STRIDE + nt * 16 + l15] = pk;
        }
    }
}

__device__ __forceinline__ void mfma_stage(f32x4 acc[2][4], const uint4* wqs,
                                           const uint4 aH[2][2], const uint4 aL[2][2], int lane) {
#pragma unroll
    for (int kt = 0; kt < 2; ++kt) {
#pragma unroll
        for (int nt = 0; nt < 4; ++nt) {
            const uint4* wq = wqs + ((size_t)((kt * 4 + nt) * 64 + lane)) * 2;
            short8v bh = as_frag(wq[0]);
            short8v bl = as_frag(wq[1]);
#pragma unroll
            for (int mt = 0; mt < 2; ++mt) {
                short8v ah = as_frag(aH[mt][kt]);
                short8v al = as_frag(aL[mt][kt]);
                acc[mt][nt] = __builtin_amdgcn_mfma_f32_16x16x32_bf16(ah, bh, acc[mt][nt], 0, 0, 0);
                acc[mt][nt] = __builtin_amdgcn_mfma_f32_16x16x32_bf16(al, bh, acc[mt][nt], 0, 0, 0);
                acc[mt][nt] = __builtin_amdgcn_mfma_f32_16x16x32_bf16(ah, bl, acc[mt][nt], 0, 0, 0);
            }
        }
    }
}

__global__ __launch_bounds__(256, 3) void k_mega(
    const float* __restrict__ ea, const int* __restrict__ src, const int* __restrict__ dst,
    const float* __restrict__ xfin, const unsigned* __restrict__ wpk, const float* __restrict__ biasArr,
    const float* __restrict__ finw, const float* __restrict__ finb, float* __restrict__ out) {
    __shared__ unsigned act_lds[4 * 2 * ACT_TILE];   // 34816 B
    const int tid = threadIdx.x;
    const int wv = tid >> 6, lane = tid & 63;
    const int g = lane >> 4, l15 = lane & 15;
    const int eb = blockIdx.x * 128 + wv * 32;       // wave's 32 edges (2 M-tiles)
    unsigned* actw = act_lds + wv * 2 * ACT_TILE;
    const uint4* wpk4 = (const uint4*)wpk;

    f32x4 acc[2][4];
    uint4 aH[2][2], aL[2][2];

    // ---- s0: e0 = relu(edge_attr @ W0pad + eb0), K padded to 64 (kt=1 slot is zeros) ----
#pragma unroll
    for (int mt = 0; mt < 2; ++mt) {
        if (g < 2) {
            const float* rowp = ea + (size_t)(eb + mt * 16 + l15) * 16;
            load_a_global_kt(rowp, 0, g, aH[mt][0], aL[mt][0]);
        } else { aH[mt][0] = zero4(); aL[mt][0] = zero4(); }
        aH[mt][1] = zero4(); aL[mt][1] = zero4();
#pragma unroll
        for (int nt = 0; nt < 4; ++nt) { float b = biasArr[nt * 16 + l15]; acc[mt][nt] = (f32x4){b, b, b, b}; }
    }
    mfma_stage(acc, wpk4, aH, aL, lane);
#pragma unroll
    for (int mt = 0; mt < 2; ++mt) write_act(actw, mt, l15, g, acc);

    // ---- s1..s7: edge MLP; s8: e-chunk of out_w0 (starts out-MLP acc, no act write) ----
    for (int s = 1; s <= 8; ++s) {
#pragma unroll
        for (int mt = 0; mt < 2; ++mt) {
            read_a_lds(actw, mt, l15, g, aH, aL);
#pragma unroll
            for (int nt = 0; nt < 4; ++nt) { float b = biasArr[s * 64 + nt * 16 + l15]; acc[mt][nt] = (f32x4){b, b, b, b}; }
        }
        mfma_stage(acc, wpk4 + (size_t)s * 1024, aH, aL, lane);
        if (s != 8) {
#pragma unroll
            for (int mt = 0; mt < 2; ++mt) write_act(actw, mt, l15, g, acc);
        }
    }

    // ---- s9: + x[src] @ ow0[0:64];  s10: + x[dst] @ ow0[64:128]  (accumulate, no reset) ----
#pragma unroll
    for (int p = 0; p < 2; ++p) {
        const int s = 9 + p;
        const int* idxp = p ? dst : src;
#pragma unroll
        for (int mt = 0; mt < 2; ++mt) {
            int node = idxp[eb + mt * 16 + l15];
            const float* rowp = xfin + (size_t)node * 64;
#pragma unroll
            for (int kt = 0; kt < 2; ++kt)
                load_a_global_kt(rowp, kt, g, aH[mt][kt], aL[mt][kt]);
        }
        mfma_stage(acc, wpk4 + (size_t)s * 1024, aH, aL, lane);
    }
#pragma unroll
    for (int mt = 0; mt < 2; ++mt) write_act(actw, mt, l15, g, acc);   // relu(f@ow0+ob0)

    // ---- s11..s13: out MLP layers (s13 keeps acc in regs for final dot) ----
    for (int s = 11; s <= 13; ++s) {
#pragma unroll
        for (int mt = 0; mt < 2; ++mt) {
            read_a_lds(actw, mt, l15, g, aH, aL);
#pragma unroll
            for (int nt = 0; nt < 4; ++nt) { float b = biasArr[s * 64 + nt * 16 + l15]; acc[mt][nt] = (f32x4){b, b, b, b}; }
        }
        mfma_stage(acc, wpk4 + (size_t)s * 1024, aH, aL, lane);
        if (s != 13) {
#pragma unroll
            for (int mt = 0; mt < 2; ++mt) write_act(actw, mt, l15, g, acc);
        }
    }

    // ---- final: out = relu(acc) . fin_w + fin_b ; reduce across 16-lane group ----
    float fw[4];
#pragma unroll
    for (int nt = 0; nt < 4; ++nt) fw[nt] = finw[nt * 16 + l15];
    const float fb = finb[0];
#pragma unroll
    for (int mt = 0; mt < 2; ++mt) {
#pragma unroll
        for (int r = 0; r < 4; ++r) {
            float v = 0.f;
#pragma unroll
            for (int nt = 0; nt < 4; ++nt) v = fmaf(fmaxf(acc[mt][nt][r], 0.f), fw[nt], v);
            v += __shfl_xor(v, 1, 64);
            v += __shfl_xor(v, 2, 64);
            v += __shfl_xor(v, 4, 64);
            v += __shfl_xor(v, 8, 64);
            if (l15 == r) out[eb + mt * 16 + g * 4 + r] = v + fb;
        }
    }
}

// ---------------- launch ----------------

extern "C" void kernel_launch(void* const* d_in, const int* in_sizes, int n_in,
                              void* d_out, int out_size, void* d_ws, size_t ws_size,
                              hipStream_t stream) {
    (void)in_sizes; (void)n_in; (void)out_size; (void)ws_size;

    const float* x         = (const float*)d_in[0];
    const int*   src       = (const int*)d_in[1];
    const int*   dst       = (const int*)d_in[2];
    const float* edge_attr = (const float*)d_in[3];
    const float* gcn_w     = (const float*)d_in[4];
    const float* gcn_b     = (const float*)d_in[5];
    const float* edge_w0   = (const float*)d_in[6];
    const float* edge_b0   = (const float*)d_in[7];
    const float* edge_w    = (const float*)d_in[8];
    const float* edge_b    = (const float*)d_in[9];
    const float* out_w0    = (const float*)d_in[10];
    const float* out_b0    = (const float*)d_in[11];
    const float* out_w     = (const float*)d_in[12];
    const float* out_b     = (const float*)d_in[13];
    const float* fin_w     = (const float*)d_in[14];
    const float* fin_b     = (const float*)d_in[15];
    float* out = (float*)d_out;

    float* ws    = (float*)d_ws;
    float* dinv  = ws;                        // N (deg first)
    float* normv = ws + 50048;                // E
    float* xb0   = normv + N_EDGES;           // N*64
    float* xb1   = xb0 + N_NODES * 64;
    float* xl    = xb1 + N_NODES * 64;
    float* agg   = xl + N_NODES * 64;
    // after GCN loop, agg region is dead -> reuse for packed weights + biases
    unsigned* wpk   = (unsigned*)agg;         // 57344 u32
    float* biasArr  = agg + 57600;            // 896 f32

    const int EB = N_EDGES / 256;             // 3125
    const int NB = (N_NODES + 255) / 256;     // 196

    hipMemsetAsync(dinv, 0, N_NODES * sizeof(float), stream);
    k_deg<<<EB, 256, 0, stream>>>(dst, dinv);
    k_dinv<<<NB, 256, 0, stream>>>(dinv);
    k_norm<<<EB, 256, 0, stream>>>(src, dst, dinv, normv);

    const float* xin = x;
    float* bufs[2] = {xb0, xb1};
    for (int layer = 0; layer < 4; ++layer) {
        float* xout = bufs[layer & 1];
        k_xl2<<<(N_NODES + 63) / 64, 256, 0, stream>>>(xin, gcn_w + layer * 4096, xl);
        hipMemsetAsync(agg, 0, (size_t)N_NODES * 64 * sizeof(float), stream);
        k_scatter<<<N_EDGES * 64 / 256, 256, 0, stream>>>(src, dst, normv, xl, agg);
        k_fin<<<N_NODES * 64 / 256, 256, 0, stream>>>(agg, xl, dinv, gcn_b + layer * 64, xout);
        xin = xout;
    }
    // final node features in xb1

    k_wprep<<<28, 256, 0, stream>>>(edge_w0, edge_w, out_w0, out_w, wpk);
    k_bprep<<<4, 256, 0, stream>>>(edge_b0, edge_b, out_b0, out_b, biasArr);

    k_mega<<<N_EDGES / 128, 256, 0, stream>>>(edge_attr, src, dst, xb1,
                                              wpk, biasArr, fin_w, fin_b, out);
}

// Round 4
// 654.196 us; speedup vs baseline: 190.6448x; 1.7954x over previous
//
#include <hip/hip_runtime.h>

#define N_NODES 50000
#define N_EDGES 800000
#define NPAD 50176   // 196*256

typedef __attribute__((ext_vector_type(8))) short short8v;   // 8 bf16 (4 VGPR)
typedef __attribute__((ext_vector_type(4))) float f32x4;

union U4S8 { uint4 u; short8v s; };
__device__ __forceinline__ short8v as_frag(uint4 u) { U4S8 t; t.u = u; return t.s; }
__device__ __forceinline__ uint4 zero4() { return make_uint4(0u, 0u, 0u, 0u); }

// ---------------- degree / norm ----------------

__global__ __launch_bounds__(256) void k_deg_i(const int* __restrict__ dst, int* __restrict__ degi) {
    int e = blockIdx.x * 256 + threadIdx.x;
    if (e < N_EDGES) atomicAdd(&degi[dst[e]], 1);
}

__global__ __launch_bounds__(256) void k_dinv(const int* __restrict__ degi, float* __restrict__ dinv) {
    int i = blockIdx.x * 256 + threadIdx.x;
    if (i < N_NODES) dinv[i] = rsqrtf((float)degi[i] + 1.0f);
}

__global__ __launch_bounds__(256) void k_norm(const int* __restrict__ src, const int* __restrict__ dst,
                                              const float* __restrict__ dinv, float* __restrict__ normv) {
    int e = blockIdx.x * 256 + threadIdx.x;
    if (e < N_EDGES) normv[e] = dinv[src[e]] * dinv[dst[e]];
}

// ---------------- CSR build: 2-level exclusive scan + bucket place ----------------

__global__ __launch_bounds__(256) void k_scan1(const int* __restrict__ degi, int* __restrict__ part,
                                               int* __restrict__ bsum) {
    __shared__ int tmp[256];
    int t = threadIdx.x, gid = blockIdx.x * 256 + t;
    int v = degi[gid];
    tmp[t] = v;
    __syncthreads();
    for (int off = 1; off < 256; off <<= 1) {
        int add = (t >= off) ? tmp[t - off] : 0;
        __syncthreads();
        tmp[t] += add;
        __syncthreads();
    }
    part[gid] = tmp[t] - v;                 // exclusive within block
    if (t == 255) bsum[blockIdx.x] = tmp[t];
}

__global__ __launch_bounds__(256) void k_scan2(int* __restrict__ bsum) {
    __shared__ int tmp[256];
    int t = threadIdx.x;
    int v = (t < 196) ? bsum[t] : 0;
    tmp[t] = v;
    __syncthreads();
    for (int off = 1; off < 256; off <<= 1) {
        int add = (t >= off) ? tmp[t - off] : 0;
        __syncthreads();
        tmp[t] += add;
        __syncthreads();
    }
    if (t < 196) bsum[t] = tmp[t] - v;      // exclusive block offsets
}

__global__ __launch_bounds__(256) void k_scan3(const int* __restrict__ part, const int* __restrict__ bsum,
                                               int* __restrict__ rowp) {
    int gid = blockIdx.x * 256 + threadIdx.x;
    rowp[gid] = part[gid] + bsum[blockIdx.x];
}

__global__ __launch_bounds__(256) void k_place(const int* __restrict__ src, const int* __restrict__ dst,
                                               const float* __restrict__ normv, const int* __restrict__ rowp,
                                               int* __restrict__ cur, int* __restrict__ es, float* __restrict__ en) {
    int e = blockIdx.x * 256 + threadIdx.x;
    if (e >= N_EDGES) return;
    int d = dst[e];
    int p = atomicAdd(&cur[d], 1);
    int slot = rowp[d] + p;
    es[slot] = src[e];
    en[slot] = normv[e];
}

// ---------------- weight / bias pre-split ----------------
// wpk (u32): [s(18)][kt(2)][nt(4)][lane(64)][8]; first 4 u32 = hi bf16x8 frag, last 4 = lo.
// s 0..13: edge pipeline (unchanged from R3); s 14..17: gcn_w layers.

__global__ __launch_bounds__(256) void k_wprep(const float* __restrict__ ew0, const float* __restrict__ ew,
                                               const float* __restrict__ ow0, const float* __restrict__ ow,
                                               const float* __restrict__ gw, unsigned* __restrict__ wpk) {
    int t = blockIdx.x * 256 + threadIdx.x;
    if (t >= 18 * 512) return;
    int lane = t & 63;
    int nt = (t >> 6) & 3;
    int kt = (t >> 8) & 1;
    int s = t >> 9;
    int n = nt * 16 + (lane & 15);
    unsigned hu[8], lu[8];
#pragma unroll
    for (int i = 0; i < 8; ++i) {
        int k = kt * 32 + ((lane >> 4) * 8) + i;
        float w = 0.f;
        if (s == 0)       { if (k < 16) w = ew0[k * 64 + n]; }
        else if (s <= 7)  w = ew[((s - 1) * 64 + k) * 64 + n];
        else if (s == 8)  w = ow0[(128 + k) * 64 + n];
        else if (s == 9)  w = ow0[k * 64 + n];
        else if (s == 10) w = ow0[(64 + k) * 64 + n];
        else if (s <= 13) w = ow[((s - 11) * 64 + k) * 64 + n];
        else              w = gw[((s - 14) * 64 + k) * 64 + n];
        unsigned u = __float_as_uint(w);
        unsigned h = u & 0xFFFF0000u;
        float d = w - __uint_as_float(h);
        hu[i] = h >> 16;
        lu[i] = __float_as_uint(d) >> 16;
    }
    uint4* o = (uint4*)(wpk + (size_t)t * 8);
    o[0] = make_uint4(hu[0] | (hu[1] << 16), hu[2] | (hu[3] << 16), hu[4] | (hu[5] << 16), hu[6] | (hu[7] << 16));
    o[1] = make_uint4(lu[0] | (lu[1] << 16), lu[2] | (lu[3] << 16), lu[4] | (lu[5] << 16), lu[6] | (lu[7] << 16));
}

__global__ __launch_bounds__(256) void k_bprep(const float* __restrict__ eb0, const float* __restrict__ eb,
                                               const float* __restrict__ ob0, const float* __restrict__ ob,
                                               float* __restrict__ biasArr) {
    int t = blockIdx.x * 256 + threadIdx.x;
    if (t >= 14 * 64) return;
    int s = t >> 6, j = t & 63;
    float b = 0.f;
    if (s == 0) b = eb0[j];
    else if (s <= 7) b = eb[(s - 1) * 64 + j];
    else if (s == 8) b = ob0[j];
    else if (s >= 11) b = ob[(s - 11) * 64 + j];
    biasArr[t] = b;
}

// ---------------- shared MFMA helpers (split bf16) ----------------

__device__ __forceinline__ void split_pack8(const float* xv, uint4& hfrag, uint4& lfrag) {
    unsigned hu[8], lu[8];
#pragma unroll
    for (int i = 0; i < 8; ++i) {
        unsigned u = __float_as_uint(xv[i]);
        unsigned h = u & 0xFFFF0000u;
        float d = xv[i] - __uint_as_float(h);
        hu[i] = h >> 16;
        lu[i] = __float_as_uint(d) >> 16;
    }
    hfrag = make_uint4(hu[0] | (hu[1] << 16), hu[2] | (hu[3] << 16), hu[4] | (hu[5] << 16), hu[6] | (hu[7] << 16));
    lfrag = make_uint4(lu[0] | (lu[1] << 16), lu[2] | (lu[3] << 16), lu[4] | (lu[5] << 16), lu[6] | (lu[7] << 16));
}

__device__ __forceinline__ void load_a_global_kt(const float* rowp, int kt, int g, uint4& aH, uint4& aL) {
    const float4* r4 = (const float4*)(rowp + kt * 32 + g * 8);
    float4 f0 = r4[0], f1 = r4[1];
    float xv[8] = {f0.x, f0.y, f0.z, f0.w, f1.x, f1.y, f1.z, f1.w};
    split_pack8(xv, aH, aL);
}

__device__ __forceinline__ void mfma_stage(f32x4 acc[2][4], const uint4* wqs,
                                           const uint4 aH[2][2], const uint4 aL[2][2], int lane) {
#pragma unroll
    for (int kt = 0; kt < 2; ++kt) {
#pragma unroll
        for (int nt = 0; nt < 4; ++nt) {
            const uint4* wq = wqs + ((size_t)((kt * 4 + nt) * 64 + lane)) * 2;
            short8v bh = as_frag(wq[0]);
            short8v bl = as_frag(wq[1]);
#pragma unroll
            for (int mt = 0; mt < 2; ++mt) {
                short8v ah = as_frag(aH[mt][kt]);
                short8v al = as_frag(aL[mt][kt]);
                acc[mt][nt] = __builtin_amdgcn_mfma_f32_16x16x32_bf16(ah, bh, acc[mt][nt], 0, 0, 0);
                acc[mt][nt] = __builtin_amdgcn_mfma_f32_16x16x32_bf16(al, bh, acc[mt][nt], 0, 0, 0);
                acc[mt][nt] = __builtin_amdgcn_mfma_f32_16x16x32_bf16(ah, bl, acc[mt][nt], 0, 0, 0);
            }
        }
    }
}

// ---------------- GCN node GEMM: xl = xin @ gcn_w[layer]  (MFMA) ----------------

__global__ __launch_bounds__(256, 3) void k_xlm(const float* __restrict__ xin,
                                                const unsigned* __restrict__ wpk, int stage,
                                                float* __restrict__ xl) {
    const int tid = threadIdx.x;
    const int wv = tid >> 6, lane = tid & 63;
    const int g = lane >> 4, l15 = lane & 15;
    const int rb = blockIdx.x * 128 + wv * 32;
    const uint4* wq = (const uint4*)wpk + (size_t)stage * 1024;

    f32x4 acc[2][4];
    uint4 aH[2][2], aL[2][2];
#pragma unroll
    for (int mt = 0; mt < 2; ++mt) {
        int row = rb + mt * 16 + l15;
        if (row < N_NODES) {
            const float* rowp = xin + (size_t)row * 64;
#pragma unroll
            for (int kt = 0; kt < 2; ++kt) load_a_global_kt(rowp, kt, g, aH[mt][kt], aL[mt][kt]);
        } else {
#pragma unroll
            for (int kt = 0; kt < 2; ++kt) { aH[mt][kt] = zero4(); aL[mt][kt] = zero4(); }
        }
#pragma unroll
        for (int nt = 0; nt < 4; ++nt) acc[mt][nt] = (f32x4){0.f, 0.f, 0.f, 0.f};
    }
    mfma_stage(acc, wq, aH, aL, lane);
#pragma unroll
    for (int mt = 0; mt < 2; ++mt)
#pragma unroll
        for (int nt = 0; nt < 4; ++nt)
#pragma unroll
            for (int r = 0; r < 4; ++r) {
                int row = rb + mt * 16 + g * 4 + r;
                if (row < N_NODES) xl[(size_t)row * 64 + nt * 16 + l15] = acc[mt][nt][r];
            }
}

// ---------------- segmented aggregation + self-loop + bias + relu ----------------
// one wave per node; lane j = output column; coalesced 256B row gathers, no atomics.

__global__ __launch_bounds__(256) void k_agg(const float* __restrict__ xl,
                                             const int* __restrict__ es, const float* __restrict__ en,
                                             const int* __restrict__ rowp, const float* __restrict__ dinv,
                                             const float* __restrict__ b, float* __restrict__ xout) {
    int n = blockIdx.x * 4 + (threadIdx.x >> 6);
    int j = threadIdx.x & 63;
    if (n >= N_NODES) return;
    int i = rowp[n], e1 = rowp[n + 1];
    float a0 = 0.f, a1 = 0.f;
    for (; i + 1 < e1; i += 2) {
        int s0 = es[i], s1 = es[i + 1];
        float w0 = en[i], w1 = en[i + 1];
        a0 = fmaf(w0, xl[(size_t)s0 * 64 + j], a0);
        a1 = fmaf(w1, xl[(size_t)s1 * 64 + j], a1);
    }
    if (i < e1) a0 = fmaf(en[i], xl[(size_t)es[i] * 64 + j], a0);
    float di = dinv[n];
    float v = a0 + a1 + di * di * xl[(size_t)n * 64 + j] + b[j];
    xout[(size_t)n * 64 + j] = fmaxf(v, 0.f);
}

// ---------------- fused edge mega kernel (unchanged from R3) ----------------

#define ACT_STRIDE 68
#define ACT_TILE (16 * ACT_STRIDE)

__device__ __forceinline__ void read_a_lds(const unsigned* actw, int mt, int l15, int g,
                                           uint4 aH[2][2], uint4 aL[2][2]) {
#pragma unroll
    for (int kt = 0; kt < 2; ++kt) {
        const unsigned* p = actw + mt * ACT_TILE + l15 * ACT_STRIDE + kt * 32 + g * 8;
        uint4 p0 = *(const uint4*)p;
        uint4 p1 = *(const uint4*)(p + 4);
        unsigned q[8] = {p0.x, p0.y, p0.z, p0.w, p1.x, p1.y, p1.z, p1.w};
        unsigned h[4], l[4];
#pragma unroll
        for (int j = 0; j < 4; ++j) {
            h[j] = (q[2 * j] >> 16) | (q[2 * j + 1] & 0xFFFF0000u);
            l[j] = (q[2 * j] & 0xFFFFu) | (q[2 * j + 1] << 16);
        }
        aH[mt][kt] = make_uint4(h[0], h[1], h[2], h[3]);
        aL[mt][kt] = make_uint4(l[0], l[1], l[2], l[3]);
    }
}

__device__ __forceinline__ void write_act(unsigned* actw, int mt, int l15, int g, f32x4 acc[2][4]) {
#pragma unroll
    for (int nt = 0; nt < 4; ++nt) {
        f32x4 a = acc[mt][nt];
#pragma unroll
        for (int r = 0; r < 4; ++r) {
            float x = fmaxf(a[r], 0.f);
            unsigned u = __float_as_uint(x);
            unsigned h = u & 0xFFFF0000u;
            float d = x - __uint_as_float(h);
            unsigned pk = h | (__float_as_uint(d) >> 16);
            actw[mt * ACT_TILE + (g * 4 + r) * ACT_STRIDE + nt * 16 + l15] = pk;
        }
    }
}

__global__ __launch_bounds__(256, 3) void k_mega(
    const float* __restrict__ ea, const int* __restrict__ src, const int* __restrict__ dst,
    const float* __restrict__ xfin, const unsigned* __restrict__ wpk, const float* __restrict__ biasArr,
    const float* __restrict__ finw, const float* __restrict__ finb, float* __restrict__ out) {
    __shared__ unsigned act_lds[4 * 2 * ACT_TILE];
    const int tid = threadIdx.x;
    const int wv = tid >> 6, lane = tid & 63;
    const int g = lane >> 4, l15 = lane & 15;
    const int eb = blockIdx.x * 128 + wv * 32;
    unsigned* actw = act_lds + wv * 2 * ACT_TILE;
    const uint4* wpk4 = (const uint4*)wpk;

    f32x4 acc[2][4];
    uint4 aH[2][2], aL[2][2];

#pragma unroll
    for (int mt = 0; mt < 2; ++mt) {
        if (g < 2) {
            const float* rowp = ea + (size_t)(eb + mt * 16 + l15) * 16;
            load_a_global_kt(rowp, 0, g, aH[mt][0], aL[mt][0]);
        } else { aH[mt][0] = zero4(); aL[mt][0] = zero4(); }
        aH[mt][1] = zero4(); aL[mt][1] = zero4();
#pragma unroll
        for (int nt = 0; nt < 4; ++nt) { float b = biasArr[nt * 16 + l15]; acc[mt][nt] = (f32x4){b, b, b, b}; }
    }
    mfma_stage(acc, wpk4, aH, aL, lane);
#pragma unroll
    for (int mt = 0; mt < 2; ++mt) write_act(actw, mt, l15, g, acc);

    for (int s = 1; s <= 8; ++s) {
#pragma unroll
        for (int mt = 0; mt < 2; ++mt) {
            read_a_lds(actw, mt, l15, g, aH, aL);
#pragma unroll
            for (int nt = 0; nt < 4; ++nt) { float b = biasArr[s * 64 + nt * 16 + l15]; acc[mt][nt] = (f32x4){b, b, b, b}; }
        }
        mfma_stage(acc, wpk4 + (size_t)s * 1024, aH, aL, lane);
        if (s != 8) {
#pragma unroll
            for (int mt = 0; mt < 2; ++mt) write_act(actw, mt, l15, g, acc);
        }
    }

#pragma unroll
    for (int p = 0; p < 2; ++p) {
        const int s = 9 + p;
        const int* idxp = p ? dst : src;
#pragma unroll
        for (int mt = 0; mt < 2; ++mt) {
            int node = idxp[eb + mt * 16 + l15];
            const float* rowp = xfin + (size_t)node * 64;
#pragma unroll
            for (int kt = 0; kt < 2; ++kt)
                load_a_global_kt(rowp, kt, g, aH[mt][kt], aL[mt][kt]);
        }
        mfma_stage(acc, wpk4 + (size_t)s * 1024, aH, aL, lane);
    }
#pragma unroll
    for (int mt = 0; mt < 2; ++mt) write_act(actw, mt, l15, g, acc);

    for (int s = 11; s <= 13; ++s) {
#pragma unroll
        for (int mt = 0; mt < 2; ++mt) {
            read_a_lds(actw, mt, l15, g, aH, aL);
#pragma unroll
            for (int nt = 0; nt < 4; ++nt) { float b = biasArr[s * 64 + nt * 16 + l15]; acc[mt][nt] = (f32x4){b, b, b, b}; }
        }
        mfma_stage(acc, wpk4 + (size_t)s * 1024, aH, aL, lane);
        if (s != 13) {
#pragma unroll
            for (int mt = 0; mt < 2; ++mt) write_act(actw, mt, l15, g, acc);
        }
    }

    float fw[4];
#pragma unroll
    for (int nt = 0; nt < 4; ++nt) fw[nt] = finw[nt * 16 + l15];
    const float fb = finb[0];
#pragma unroll
    for (int mt = 0; mt < 2; ++mt) {
#pragma unroll
        for (int r = 0; r < 4; ++r) {
            float v = 0.f;
#pragma unroll
            for (int nt = 0; nt < 4; ++nt) v = fmaf(fmaxf(acc[mt][nt][r], 0.f), fw[nt], v);
            v += __shfl_xor(v, 1, 64);
            v += __shfl_xor(v, 2, 64);
            v += __shfl_xor(v, 4, 64);
            v += __shfl_xor(v, 8, 64);
            if (l15 == r) out[eb + mt * 16 + g * 4 + r] = v + fb;
        }
    }
}

// ---------------- launch ----------------

extern "C" void kernel_launch(void* const* d_in, const int* in_sizes, int n_in,
                              void* d_out, int out_size, void* d_ws, size_t ws_size,
                              hipStream_t stream) {
    (void)in_sizes; (void)n_in; (void)out_size; (void)ws_size;

    const float* x         = (const float*)d_in[0];
    const int*   src       = (const int*)d_in[1];
    const int*   dst       = (const int*)d_in[2];
    const float* edge_attr = (const float*)d_in[3];
    const float* gcn_w     = (const float*)d_in[4];
    const float* gcn_b     = (const float*)d_in[5];
    const float* edge_w0   = (const float*)d_in[6];
    const float* edge_b0   = (const float*)d_in[7];
    const float* edge_w    = (const float*)d_in[8];
    const float* edge_b    = (const float*)d_in[9];
    const float* out_w0    = (const float*)d_in[10];
    const float* out_b0    = (const float*)d_in[11];
    const float* out_w     = (const float*)d_in[12];
    const float* out_b     = (const float*)d_in[13];
    const float* fin_w     = (const float*)d_in[14];
    const float* fin_b     = (const float*)d_in[15];
    float* out = (float*)d_out;

    float* ws    = (float*)d_ws;
    float* dinv  = ws;                        // NPAD
    float* normv = ws + NPAD;                 // E
    float* xb0   = normv + N_EDGES;           // N*64
    float* xb1   = xb0 + N_NODES * 64;
    float* xl    = xb1 + N_NODES * 64;
    float* scr   = xl + N_NODES * 64;         // scratch region (~7.5MB)

    unsigned* wpk  = (unsigned*)scr;          // 18*512*8 = 73728
    float* biasArr = scr + 73728;             // 896
    int* degi      = (int*)(scr + 74624);     // NPAD
    int* part      = degi + NPAD;             // NPAD
    int* bsum      = part + NPAD;             // 256
    int* rowp      = bsum + 256;              // NPAD
    int* cur       = rowp + NPAD;             // NPAD
    int* es        = cur + NPAD;              // E
    float* en      = (float*)(es + N_EDGES);  // E

    const int EB = N_EDGES / 256;             // 3125
    const int NB = (N_NODES + 255) / 256;     // 196 (also NPAD/256)

    hipMemsetAsync(degi, 0, NPAD * sizeof(int), stream);
    hipMemsetAsync(cur, 0, NPAD * sizeof(int), stream);
    k_deg_i<<<EB, 256, 0, stream>>>(dst, degi);
    k_dinv<<<NB, 256, 0, stream>>>(degi, dinv);
    k_norm<<<EB, 256, 0, stream>>>(src, dst, dinv, normv);
    k_scan1<<<196, 256, 0, stream>>>(degi, part, bsum);
    k_scan2<<<1, 256, 0, stream>>>(bsum);
    k_scan3<<<196, 256, 0, stream>>>(part, bsum, rowp);
    k_place<<<EB, 256, 0, stream>>>(src, dst, normv, rowp, cur, es, en);

    k_wprep<<<36, 256, 0, stream>>>(edge_w0, edge_w, out_w0, out_w, gcn_w, wpk);
    k_bprep<<<4, 256, 0, stream>>>(edge_b0, edge_b, out_b0, out_b, biasArr);

    const float* xin = x;
    float* bufs[2] = {xb0, xb1};
    for (int layer = 0; layer < 4; ++layer) {
        float* xout = bufs[layer & 1];
        k_xlm<<<(NPAD / 128), 256, 0, stream>>>(xin, wpk, 14 + layer, xl);
        k_agg<<<(N_NODES + 3) / 4, 256, 0, stream>>>(xl, es, en, rowp, dinv,
                                                     gcn_b + layer * 64, xout);
        xin = xout;
    }
    // final node features in xb1

    k_mega<<<N_EDGES / 128, 256, 0, stream>>>(edge_attr, src, dst, xb1,
                                              wpk, biasArr, fin_w, fin_b, out);
}